// Round 1
// baseline (509.621 us; speedup 1.0000x reference)
//
#include <hip/hip_runtime.h>
#include <cstdint>
#include <math.h>

#define ROW_LEN 4096
#define KSEL 8
#define NTHREADS 256

__global__ __launch_bounds__(NTHREADS) void kmax_kernel(const float* __restrict__ in,
                                                        float* __restrict__ out) {
    const int row = blockIdx.x;
    const int tid = threadIdx.x;

    // Coalesced load: chunk j is a contiguous wave-wide float4 run.
    // Element mapping: slot s = j*4+c  ->  global idx gi = j*1024 + tid*4 + c
    // gi bit layout: [1:0]=c, [9:2]=tid, [11:10]=j
    const float4* p4 = reinterpret_cast<const float4*>(in + (size_t)row * ROW_LEN);
    float v[16];
#pragma unroll
    for (int j = 0; j < 4; ++j) {
        float4 a = p4[j * NTHREADS + tid];
        v[j * 4 + 0] = a.x;
        v[j * 4 + 1] = a.y;
        v[j * 4 + 2] = a.z;
        v[j * 4 + 3] = a.w;
    }

    __shared__ float sv[KSEL][4];
    __shared__ int   si[KSEL][4];

    unsigned mask = 0;        // per-thread: which of my 16 slots are already taken
    float selV[KSEL];
    int   selI[KSEL];

    for (int it = 0; it < KSEL; ++it) {
        // ---- local masked argmax over my 16 elements (tie -> lowest index) ----
        float bv = -INFINITY;
        int   bi = 0x7fffffff;
#pragma unroll
        for (int s = 0; s < 16; ++s) {
            if (!(mask & (1u << s))) {
                int   gi  = ((s >> 2) << 10) | (tid << 2) | (s & 3);
                float val = v[s];
                if (val > bv || (val == bv && gi < bi)) { bv = val; bi = gi; }
            }
        }
        // ---- wave (64-lane) reduce of (val, idx) ----
#pragma unroll
        for (int off = 32; off > 0; off >>= 1) {
            float ov = __shfl_xor(bv, off, 64);
            int   oi = __shfl_xor(bi, off, 64);
            if (ov > bv || (ov == bv && oi < bi)) { bv = ov; bi = oi; }
        }
        // ---- cross-wave combine via LDS (per-iteration slots: 1 barrier/iter) ----
        const int wave = tid >> 6;
        if ((tid & 63) == 0) { sv[it][wave] = bv; si[it][wave] = bi; }
        __syncthreads();
        float fv = sv[it][0];
        int   fi = si[it][0];
#pragma unroll
        for (int w = 1; w < 4; ++w) {
            float ov = sv[it][w];
            int   oi = si[it][w];
            if (ov > fv || (ov == fv && oi < fi)) { fv = ov; fi = oi; }
        }
        selV[it] = fv;
        selI[it] = fi;
        // owner thread masks the winning slot
        if (((fi >> 2) & 255) == tid) {
            int slot = ((fi >> 10) << 2) | (fi & 3);
            mask |= (1u << slot);
        }
    }

    // ---- restore positional order: unrolled bubble sort by index, thread 0 writes ----
    if (tid == 0) {
#pragma unroll
        for (int i = 0; i < KSEL; ++i) {
#pragma unroll
            for (int j = 0; j < KSEL - 1; ++j) {
                if (j < KSEL - 1 - i && selI[j] > selI[j + 1]) {
                    int   ti = selI[j]; selI[j] = selI[j + 1]; selI[j + 1] = ti;
                    float tv = selV[j]; selV[j] = selV[j + 1]; selV[j + 1] = tv;
                }
            }
        }
        float* o = out + (size_t)row * KSEL;
#pragma unroll
        for (int i = 0; i < KSEL; ++i) o[i] = selV[i];
    }
}

extern "C" void kernel_launch(void* const* d_in, const int* in_sizes, int n_in,
                              void* d_out, int out_size, void* d_ws, size_t ws_size,
                              hipStream_t stream) {
    const float* in  = (const float*)d_in[0];
    float*       out = (float*)d_out;
    const int rows = in_sizes[0] / ROW_LEN;  // 32*512 = 16384
    kmax_kernel<<<rows, NTHREADS, 0, stream>>>(in, out);
}

// Round 2
// 355.366 us; speedup vs baseline: 1.4341x; 1.4341x over previous
//
#include <hip/hip_runtime.h>
#include <cstdint>
#include <math.h>

#define ROW_LEN 4096
#define KSEL 8
#define NT 256
#define EPT 16   // elements per thread; thread t owns indices [t*16, t*16+16)

__device__ inline unsigned umaxu(unsigned a, unsigned b) { return a > b ? a : b; }
__device__ inline unsigned uminu(unsigned a, unsigned b) { return a > b ? b : a; }
// order-preserving fp32 -> u32 (no NaN/Inf in input)
__device__ inline unsigned ordkey(float f) {
    int t = __float_as_int(f);
    return (unsigned)(t ^ ((t >> 31) | 0x80000000));
}
__device__ inline float unkey(unsigned u) {
    int t = (int)u;
    return __int_as_float(t < 0 ? (t ^ 0x80000000) : ~t);
}

__global__ __launch_bounds__(NT) void kmax_kernel(const float* __restrict__ in,
                                                  float* __restrict__ out) {
    const int row  = blockIdx.x;
    const int tid  = threadIdx.x;
    const int lane = tid & 63;
    const int wave = tid >> 6;

    // thread-contiguous ownership: 4x float4 at [t*16 + 4j]
    const float4* p4 = reinterpret_cast<const float4*>(in + (size_t)row * ROW_LEN + (size_t)tid * EPT);

    unsigned k[EPT];
#pragma unroll
    for (int j = 0; j < 4; ++j) {
        float4 a = p4[j];
        k[j * 4 + 0] = ordkey(a.x);
        k[j * 4 + 1] = ordkey(a.y);
        k[j * 4 + 2] = ordkey(a.z);
        k[j * 4 + 3] = ordkey(a.w);
    }

    // ---- per-thread sorted (desc) top-8 of 16, values only ----
    unsigned t[EPT];
#pragma unroll
    for (int s = 0; s < EPT; ++s) t[s] = k[s];

#define CED(i, j) { unsigned a_ = t[i], b_ = t[j]; t[i] = umaxu(a_, b_); t[j] = uminu(a_, b_); }
#define SORT8D(o) \
    CED(o+0,o+1) CED(o+2,o+3) CED(o+4,o+5) CED(o+6,o+7) \
    CED(o+0,o+2) CED(o+1,o+3) CED(o+4,o+6) CED(o+5,o+7) \
    CED(o+1,o+2) CED(o+5,o+6) \
    CED(o+0,o+4) CED(o+1,o+5) CED(o+2,o+6) CED(o+3,o+7) \
    CED(o+2,o+4) CED(o+3,o+5) \
    CED(o+1,o+2) CED(o+3,o+4) CED(o+5,o+6)

    SORT8D(0)
    SORT8D(8)
    // top-8 multiset of the two sorted-8 lists -> bitonic sequence in t[0..7]
#pragma unroll
    for (int s = 0; s < 8; ++s) t[s] = umaxu(t[s], t[15 - s]);
    // bitonic merge (desc) of 8
    CED(0,4) CED(1,5) CED(2,6) CED(3,7)
    CED(0,2) CED(1,3) CED(4,6) CED(5,7)
    CED(0,1) CED(2,3) CED(4,5) CED(6,7)

    // ---- 8 extraction rounds on list heads -> T = 8th largest w/ multiplicity ----
    __shared__ unsigned sred[KSEL][4];
    __shared__ unsigned swsum[4];

    unsigned Tkey = 0;
#pragma unroll
    for (int it = 0; it < KSEL; ++it) {
        unsigned h = t[0];
        unsigned m = h;
#pragma unroll
        for (int off = 32; off > 0; off >>= 1)
            m = umaxu(m, (unsigned)__shfl_xor((int)m, off, 64));
        if (lane == 0) sred[it][wave] = m;
        __syncthreads();
        unsigned m0 = sred[it][0], m1 = sred[it][1], m2 = sred[it][2], m3 = sred[it][3];
        unsigned M = umaxu(umaxu(m0, m1), umaxu(m2, m3));
        // unique winner: first wave holding M, first lane in it with head==M
        int wsel = (m0 == M) ? 0 : (m1 == M) ? 1 : (m2 == M) ? 2 : 3;
        bool cand = (wave == wsel) && (h == M);
        unsigned long long b = __ballot(cand);
        bool amFirst = cand && ((b & ((1ull << lane) - 1)) == 0ull);
        if (amFirst) {  // pop my list
            t[0] = t[1]; t[1] = t[2]; t[2] = t[3]; t[3] = t[4];
            t[4] = t[5]; t[5] = t[6]; t[6] = t[7]; t[7] = 0u;
        }
        Tkey = M;  // value after final iteration is the threshold
    }

    // ---- gather: select (key > T) plus first (8 - total_gt) keys == T by index ----
    int cgt = 0, ceq = 0;
#pragma unroll
    for (int s = 0; s < EPT; ++s) {
        cgt += (k[s] > Tkey);
        ceq += (k[s] == Tkey);
    }
    unsigned packed = ((unsigned)cgt << 16) | (unsigned)ceq;
    unsigned p = packed;  // inclusive prefix within wave
#pragma unroll
    for (int off = 1; off < 64; off <<= 1) {
        unsigned o = (unsigned)__shfl_up((int)p, off, 64);
        if (lane >= off) p += o;
    }
    if (lane == 63) swsum[wave] = p;
    __syncthreads();
    unsigned basep = 0, total = 0;
#pragma unroll
    for (int w = 0; w < 4; ++w) {
        unsigned ws = swsum[w];
        total += ws;
        if (w < wave) basep += ws;
    }
    unsigned excl = basep + p - packed;
    int totgt = (int)(total >> 16), toteq = (int)(total & 0xFFFFu);
    int pgt = (int)(excl >> 16), peq = (int)(excl & 0xFFFFu);
    int Q = KSEL - totgt;  // # of ==T elements to take (>=1)
    int mybase = pgt + (peq < Q ? peq : Q);
    float* op = out + (size_t)row * KSEL + mybase;

    if (totgt + toteq == KSEL) {
        // common case: all >=T selected
#pragma unroll
        for (int s = 0; s < EPT; ++s) {
            if (k[s] >= Tkey) { *op++ = unkey(k[s]); }
        }
    } else {
        int myq = Q - peq; myq = myq < 0 ? 0 : myq;
        int eqSeen = 0;
#pragma unroll
        for (int s = 0; s < EPT; ++s) {
            bool iseq = (k[s] == Tkey);
            bool sel = (k[s] > Tkey) || (iseq && (eqSeen < myq));
            eqSeen += iseq;
            if (sel) { *op++ = unkey(k[s]); }
        }
    }
}

extern "C" void kernel_launch(void* const* d_in, const int* in_sizes, int n_in,
                              void* d_out, int out_size, void* d_ws, size_t ws_size,
                              hipStream_t stream) {
    const float* in  = (const float*)d_in[0];
    float*       out = (float*)d_out;
    const int rows = in_sizes[0] / ROW_LEN;  // 32*512 = 16384
    kmax_kernel<<<rows, NT, 0, stream>>>(in, out);
}